// Round 2
// baseline (19.702 us; speedup 1.0000x reference)
//
#include <hip/hip_runtime.h>
#include <hip/hip_bf16.h>

typedef _Float16 f16x8 __attribute__((ext_vector_type(8)));
typedef __fp16  fp16x2 __attribute__((ext_vector_type(2)));
typedef float f32x4 __attribute__((ext_vector_type(4)));

#define N_ROWS 65536
#define IN_F 128
#define OUT_F 16
#define NB 16
// K = IN_F * NB = 2048, K-step = 32 (one mfma), K-pair = 64 (two mfma, one recurrence)

// K permutation: K-step ks (0..63): half = ks&1, p = ks>>1.
//   slot s = 8*g + j (g = lane>>4, j = 0..7) -> feature f = 4*p + g, basis n = 8*half + j.
// So within one K-step every lane group holds ONE feature, and the n-half is
// wave-uniform; a K-pair (2p, 2p+1) needs one Chebyshev recurrence per lane.

// prep: w [16][128][16] f32 -> f16 B-fragments in frag order:
//   wf[(ks*64 + l)*8 + j] = w[o=l&15][f=4*(ks>>1)+(l>>4)][n=8*(ks&1)+j]
__global__ void prep_w_kernel(const float* __restrict__ w, _Float16* __restrict__ wf) {
    int q = blockIdx.x * 256 + threadIdx.x;   // 0..32767
    int j = q & 7;
    int l = (q >> 3) & 63;
    int ks = q >> 9;                           // 0..63
    int half = ks & 1;
    int p = ks >> 1;
    int o = l & 15;
    int g = l >> 4;
    int f = 4 * p + g;
    int n = 8 * half + j;
    wf[q] = (_Float16)w[(o * IN_F + f) * NB + n];
}

__device__ __forceinline__ void cheb_frags(float xv, f16x8& ae, f16x8& ao) {
    float x2 = xv + xv;
    float t2  = __builtin_fmaf(x2, xv,  -1.0f);
    float t3  = __builtin_fmaf(x2, t2,  -xv);
    float t4  = __builtin_fmaf(x2, t3,  -t2);
    float t5  = __builtin_fmaf(x2, t4,  -t3);
    float t6  = __builtin_fmaf(x2, t5,  -t4);
    float t7  = __builtin_fmaf(x2, t6,  -t5);
    float t8  = __builtin_fmaf(x2, t7,  -t6);
    float t9  = __builtin_fmaf(x2, t8,  -t7);
    float t10 = __builtin_fmaf(x2, t9,  -t8);
    float t11 = __builtin_fmaf(x2, t10, -t9);
    float t12 = __builtin_fmaf(x2, t11, -t10);
    float t13 = __builtin_fmaf(x2, t12, -t11);
    float t14 = __builtin_fmaf(x2, t13, -t12);
    float t15 = __builtin_fmaf(x2, t14, -t13);
    union { f16x8 v; fp16x2 h[4]; } e, od;
    e.h[0]  = __builtin_amdgcn_cvt_pkrtz(1.0f, xv);
    e.h[1]  = __builtin_amdgcn_cvt_pkrtz(t2,  t3);
    e.h[2]  = __builtin_amdgcn_cvt_pkrtz(t4,  t5);
    e.h[3]  = __builtin_amdgcn_cvt_pkrtz(t6,  t7);
    od.h[0] = __builtin_amdgcn_cvt_pkrtz(t8,  t9);
    od.h[1] = __builtin_amdgcn_cvt_pkrtz(t10, t11);
    od.h[2] = __builtin_amdgcn_cvt_pkrtz(t12, t13);
    od.h[3] = __builtin_amdgcn_cvt_pkrtz(t14, t15);
    ae = e.v;
    ao = od.v;
}

// block = 256 threads = 4 waves; wave = 32 rows (2 x 16-row MFMA tiles);
// block = 128 rows; grid = 512 (2 blocks/CU, LDS 64 KB each).
__global__ __launch_bounds__(256) void cheb_main(const float* __restrict__ x,
                                                 const _Float16* __restrict__ wf,
                                                 float* __restrict__ out) {
    __shared__ float xs[128 * 128];            // 64 KB, XOR-swizzled columns
    const int tid = threadIdx.x;
    const long row0 = (long)blockIdx.x * 128;

    // stage x: 128 rows x 128 cols, fully coalesced float4, swizzle col^((row&7)<<2)
    const float4* xg = (const float4*)(x + row0 * IN_F);
    #pragma unroll
    for (int it = 0; it < 16; ++it) {
        int idx = it * 256 + tid;              // float4 index, 4096 total
        int r = idx >> 5;                      // 32 float4 per row
        int c4 = (idx & 31) << 2;
        float4 v = xg[idx];
        *(float4*)&xs[r * 128 + (c4 ^ ((r & 7) << 2))] = v;
    }
    __syncthreads();

    const int l  = tid & 63;
    const int wv = tid >> 6;
    const int g  = l >> 4;                     // lane group -> feature offset
    const int o  = l & 15;                     // output column (C/D col = lane&15)
    const int lm = l & 15;                     // A row within tile (A row = lane&15)
    const int sw = l & 7;                      // row swizzle key (r0&7 == r1&7 == l&7)

    const int r0 = wv * 32 + lm;
    const int r1 = r0 + 16;

    f32x4 acc0 = {0.f, 0.f, 0.f, 0.f};
    f32x4 acc1 = {0.f, 0.f, 0.f, 0.f};

    const f16x8* wfv = (const f16x8*)wf;

    #pragma unroll 2
    for (int p = 0; p < 32; ++p) {
        // B-fragments for K-steps 2p (T0..7 half) and 2p+1 (T8..15 half)
        f16x8 b0 = wfv[(2 * p) * 64 + l];
        f16x8 b1 = wfv[(2 * p) * 64 + 64 + l];
        // swizzled column of feature f = (p<<2)|g  ->  ((p^sw)<<2)|g
        int col = ((p ^ sw) << 2) | g;
        float x0 = xs[r0 * 128 + col];
        float x1 = xs[r1 * 128 + col];
        f16x8 a0e, a0o, a1e, a1o;
        cheb_frags(x0, a0e, a0o);
        cheb_frags(x1, a1e, a1o);
        acc0 = __builtin_amdgcn_mfma_f32_16x16x32_f16(a0e, b0, acc0, 0, 0, 0);
        acc0 = __builtin_amdgcn_mfma_f32_16x16x32_f16(a0o, b1, acc0, 0, 0, 0);
        acc1 = __builtin_amdgcn_mfma_f32_16x16x32_f16(a1e, b0, acc1, 0, 0, 0);
        acc1 = __builtin_amdgcn_mfma_f32_16x16x32_f16(a1o, b1, acc1, 0, 0, 0);
    }

    // C/D layout: col = lane&15 (=o), row = 4*(lane>>4) + reg
    float* op = out + (row0 + wv * 32 + 4 * g) * OUT_F + o;
    #pragma unroll
    for (int rr = 0; rr < 4; ++rr) {
        op[rr * OUT_F] = acc0[rr];
        op[(16 + rr) * OUT_F] = acc1[rr];
    }
}

extern "C" void kernel_launch(void* const* d_in, const int* in_sizes, int n_in,
                              void* d_out, int out_size, void* d_ws, size_t ws_size,
                              hipStream_t stream) {
    const float* x = (const float*)d_in[0];
    const float* w = (const float*)d_in[1];
    float* out = (float*)d_out;
    _Float16* wf = (_Float16*)d_ws;            // 64 KB of scratch

    prep_w_kernel<<<128, 256, 0, stream>>>(w, wf);
    cheb_main<<<512, 256, 0, stream>>>(x, wf, out);
}